// Round 9
// baseline (457.761 us; speedup 1.0000x reference)
//
#include <hip/hip_runtime.h>
#include <hip/hip_fp16.h>

#define NN 50000
#define NE 800000
#define D 128
#define GEMM_BLOCKS 3128   // 782 * 4
#define NBKT 64       // fine dst buckets per graph
#define BW 782        // bucket width (64*782 = 50048 >= NN)
#define BCAP 16384    // per-bucket capacity (expected ~12.5K, sigma ~112)

typedef _Float16 half8_t __attribute__((ext_vector_type(8)));
typedef _Float16 half4_t __attribute__((ext_vector_type(4)));
typedef float f32x4 __attribute__((ext_vector_type(4)));

// ---------------- K0: init bcnt + summary slots + W transpose + inverse perms ----------------
__global__ void k_init(float* s1, float* s2, int* bcnt,
                       const float* __restrict__ W1, const float* __restrict__ W2,
                       _Float16* wt1, _Float16* wt2,
                       const int* __restrict__ perm1, const int* __restrict__ perm2,
                       int* pinv1, int* pinv2) {
    int i = blockIdx.x * 256 + threadIdx.x;   // grid 196*256 = 50176
    if (i < NN) { pinv1[perm1[i]] = i; pinv2[perm2[i]] = i; }
    if (i < 2 * NBKT) bcnt[i] = 0;
    if (i < D) { s1[i] = 0.f; s2[i] = 0.f; }
    if (i < 16384) {
        int n = i >> 7, k = i & 127;
        wt1[n * 128 + k] = (_Float16)W1[k * 128 + n];
        wt2[n * 128 + k] = (_Float16)W2[k * 128 + n];
    }
}

// ---------------- K1: bucket edges into 64 fine dst-ranges (int2-packed, one 8B store) ----------------
__global__ void k_bucket(const int* __restrict__ src1, const int* __restrict__ dst1,
                         const int* __restrict__ src2, const int* __restrict__ dst2,
                         int* bcnt, int2* bsd1, int2* bsd2) {
    __shared__ int lcnt[128], lpos[128], gbase[128];
    int t = threadIdx.x;
    if (t < 128) { lcnt[t] = 0; lpos[t] = 0; }
    __syncthreads();

    int e0 = blockIdx.x * 256 + t;
    int s1v0=0,d1v0=0,s2v0=0,d2v0=0, s1v1=0,d1v1=0,s2v1=0,d2v1=0;
    int s1v2=0,d1v2=0,s2v2=0,d2v2=0, s1v3=0,d1v3=0,s2v3=0,d2v3=0;
    bool v0 = (e0 + 0 * 262144) < NE;
    bool v1 = (e0 + 1 * 262144) < NE;
    bool v2 = (e0 + 2 * 262144) < NE;
    bool v3 = (e0 + 3 * 262144) < NE;
    if (v0) { int e = e0;             s1v0 = src1[e]; d1v0 = dst1[e]; s2v0 = src2[e]; d2v0 = dst2[e]; }
    if (v1) { int e = e0 + 262144;    s1v1 = src1[e]; d1v1 = dst1[e]; s2v1 = src2[e]; d2v1 = dst2[e]; }
    if (v2) { int e = e0 + 2*262144;  s1v2 = src1[e]; d1v2 = dst1[e]; s2v2 = src2[e]; d2v2 = dst2[e]; }
    if (v3) { int e = e0 + 3*262144;  s1v3 = src1[e]; d1v3 = dst1[e]; s2v3 = src2[e]; d2v3 = dst2[e]; }

    if (v0) { atomicAdd(&lcnt[d1v0 / BW], 1); atomicAdd(&lcnt[NBKT + d2v0 / BW], 1); }
    if (v1) { atomicAdd(&lcnt[d1v1 / BW], 1); atomicAdd(&lcnt[NBKT + d2v1 / BW], 1); }
    if (v2) { atomicAdd(&lcnt[d1v2 / BW], 1); atomicAdd(&lcnt[NBKT + d2v2 / BW], 1); }
    if (v3) { atomicAdd(&lcnt[d1v3 / BW], 1); atomicAdd(&lcnt[NBKT + d2v3 / BW], 1); }
    __syncthreads();
    if (t < 128) gbase[t] = atomicAdd(&bcnt[t], lcnt[t]);
    __syncthreads();

    #define PLACE(sv, dv) { \
        int r = (dv) / BW; \
        int p = gbase[r] + atomicAdd(&lpos[r], 1); \
        if (p < BCAP) bsd1[r * BCAP + p] = make_int2((sv), (dv)); }
    #define PLACE2(sv, dv) { \
        int r = (dv) / BW; \
        int p = gbase[NBKT + r] + atomicAdd(&lpos[NBKT + r], 1); \
        if (p < BCAP) bsd2[r * BCAP + p] = make_int2((sv), (dv)); }
    if (v0) { PLACE(s1v0, d1v0); PLACE2(s2v0, d2v0); }
    if (v1) { PLACE(s1v1, d1v1); PLACE2(s2v1, d2v1); }
    if (v2) { PLACE(s1v2, d1v2); PLACE2(s2v2, d2v2); }
    if (v3) { PLACE(s1v3, d1v3); PLACE2(s2v3, d2v3); }
    #undef PLACE
    #undef PLACE2
}

// ---------------- K2: build CSR per bucket entirely in LDS (zero global atomics) ----------------
__launch_bounds__(512)
__global__ void k_build(const int* __restrict__ bcnt,
                        const int2* __restrict__ bsd1, const int2* __restrict__ bsd2,
                        int* rp1, int* rp2, int* col1, int* col2,
                        float* dinv1, float* dinv2) {
    __shared__ int h[1024];
    __shared__ int tsum[512];
    __shared__ int tb[64];
    __shared__ int bbase;
    int t = threadIdx.x;
    int g = blockIdx.x >> 6;         // graph
    int f = blockIdx.x & 63;         // bucket
    const int2* bsd = (g ? bsd2 : bsd1) + f * BCAP;
    int* rp = g ? rp2 : rp1;
    int* col = g ? col2 : col1;
    float* dinv = g ? dinv2 : dinv1;
    int n = bcnt[g * NBKT + f];
    if (n > BCAP) n = BCAP;

    h[t] = 0; h[t + 512] = 0;
    if (t < NBKT) tb[t] = bcnt[g * NBKT + t];
    __syncthreads();

    for (int i = t; i < n; i += 512) atomicAdd(&h[bsd[i].y - f * BW], 1);
    __syncthreads();
    if (t == 0) { int b = 0; for (int j = 0; j < f; j++) b += tb[j]; bbase = b; }

    int a0 = h[2 * t], a1 = h[2 * t + 1];
    int s = a0 + a1;
    tsum[t] = s;
    __syncthreads();
    for (int off = 1; off < 512; off <<= 1) {
        int add = (t >= off) ? tsum[t - off] : 0;
        __syncthreads();
        tsum[t] += add;
        __syncthreads();
    }
    int excl = tsum[t] - s + bbase;
    int idx = 2 * t, gd = f * BW + idx;
    int e0 = excl, e1 = excl + a0;
    h[2 * t] = e0; h[2 * t + 1] = e1;     // histogram slots become absolute cursors
    if (idx < BW && gd < NN)         { rp[gd]     = e0; dinv[gd]     = rsqrtf((float)(a0 + 1)); }
    if (idx + 1 < BW && gd + 1 < NN) { rp[gd + 1] = e1; dinv[gd + 1] = rsqrtf((float)(a1 + 1)); }
    if (f == 63 && t == 0) rp[NN] = NE;
    __syncthreads();

    for (int i = t; i < n; i += 512) {
        int2 e = bsd[i];
        int p = atomicAdd(&h[e.y - f * BW], 1);   // LDS cursor
        col[p] = e.x;
    }
}

// ---------------- K3: 4 GEMMs, all branches stream x/mask in NATURAL order ----------------
// Neg branches: compute natural row, scatter output to pinv[row] (R8-verified, ~+27us).
__launch_bounds__(256)
__global__ void k_gemm(const _Float16* __restrict__ wt1, const _Float16* __restrict__ wt2,
                       const float* __restrict__ x,
                       const float* __restrict__ mp1, const float* __restrict__ mn1,
                       const float* __restrict__ mp2, const float* __restrict__ mn2,
                       const int* __restrict__ pinv1, const int* __restrict__ pinv2,
                       const float* __restrict__ dinv1, const float* __restrict__ dinv2,
                       _Float16* xwi1, _Float16* xwi2) {
    __shared__ __align__(16) _Float16 ST[4][16][136];   // per-wave private transpose scratch

    int g = blockIdx.x;                    // 0..3127
    int which = g / 782;                   // 0 = pos1, 1 = neg1, 2 = pos2, 3 = neg2
    int bx = g - which * 782;
    const _Float16* wt = (which < 2) ? wt1 : wt2;
    const float* mask = (which == 0) ? mp1 : (which == 1) ? mn1 : (which == 2) ? mp2 : mn2;
    const int* pinv = (which == 1) ? pinv1 : (which == 3) ? pinv2 : nullptr;
    const float* dinv = (which < 2) ? dinv1 : dinv2;
    _Float16* out = ((which < 2) ? xwi1 : xwi2) + ((which & 1) ? 128 : 0);

    int t = threadIdx.x;
    int wave = t >> 6;
    int lane = t & 63;
    int quad = lane >> 4;
    int m = lane & 15;
    int tile = bx * 4 + wave;
    if (tile * 16 >= NN) return;           // no barriers -> safe early return

    int row = tile * 16 + m;               // natural compute row (streaming reads)
    const float* xrow = x + (long)row * D;
    const float* mrow = mask + (long)row * D;

    half8_t a[4];
    #pragma unroll
    for (int kk = 0; kk < 4; kk++) {
        int k0 = kk * 32 + quad * 8;
        f32x4 xa = *(const f32x4*)(xrow + k0);
        f32x4 xb = *(const f32x4*)(xrow + k0 + 4);
        f32x4 ma = __builtin_nontemporal_load((const f32x4*)(mrow + k0));
        f32x4 mb = __builtin_nontemporal_load((const f32x4*)(mrow + k0 + 4));
        a[kk][0] = (_Float16)(xa[0] * ma[0]);
        a[kk][1] = (_Float16)(xa[1] * ma[1]);
        a[kk][2] = (_Float16)(xa[2] * ma[2]);
        a[kk][3] = (_Float16)(xa[3] * ma[3]);
        a[kk][4] = (_Float16)(xb[0] * mb[0]);
        a[kk][5] = (_Float16)(xb[1] * mb[1]);
        a[kk][6] = (_Float16)(xb[2] * mb[2]);
        a[kk][7] = (_Float16)(xb[3] * mb[3]);
    }

    // Swapped operands: A = W-fragment (out-col), B = x-fragment (x-row).
    f32x4 accs[8];
    #pragma unroll
    for (int nt = 0; nt < 8; nt++) {
        const _Float16* wrow = wt + (nt * 16 + m) * 128 + quad * 8;
        f32x4 acc = {0.f, 0.f, 0.f, 0.f};
        #pragma unroll
        for (int kk = 0; kk < 4; kk++) {
            half8_t w = *(const half8_t*)(wrow + kk * 32);
            acc = __builtin_amdgcn_mfma_f32_16x16x32_f16(w, a[kk], acc, 0, 0, 0);
        }
        accs[nt] = acc;
    }

    // Output row: natural for pos, pinv-scattered for neg.
    int orow = pinv ? pinv[row] : row;
    float ds = dinv[orow];
    _Float16* st = &ST[wave][0][0];

    #pragma unroll
    for (int nt = 0; nt < 8; nt++) {
        half4_t h;
        h[0] = (_Float16)(accs[nt][0] * ds);
        h[1] = (_Float16)(accs[nt][1] * ds);
        h[2] = (_Float16)(accs[nt][2] * ds);
        h[3] = (_Float16)(accs[nt][3] * ds);
        *(half4_t*)(st + m * 136 + nt * 16 + quad * 4) = h;
    }
    // Read back row-contiguous: each lane stores 16B chunks of ITS row orow.
    #pragma unroll
    for (int p = 0; p < 4; p++) {
        int cc = (lane >> 4) + p * 4;       // 16B chunk index 0..15
        half8_t v = *(const half8_t*)(st + m * 136 + cc * 8);
        *(half8_t*)(out + (long)orow * 256 + cc * 8) = v;
    }
}

// ---------------- K5: CSR gather aggregation + bias + ReLU (R7 body: no atomics, no barrier) ----------------
__launch_bounds__(256)
__global__ void k_agg(const _Float16* __restrict__ xwi1, const _Float16* __restrict__ xwi2,
                      const int* __restrict__ rp1, const int* __restrict__ col1,
                      const float* __restrict__ dinv1,
                      const int* __restrict__ rp2, const int* __restrict__ col2,
                      const float* __restrict__ dinv2,
                      const float* __restrict__ b1, const float* __restrict__ b2,
                      float* out) {
    int g = blockIdx.y;
    const _Float16* xwi = g ? xwi2 : xwi1;
    const int* rp = g ? rp2 : rp1;
    const int* col = g ? col2 : col1;
    const float* dinv = g ? dinv2 : dinv1;
    const float* bias = g ? b2 : b1;
    float* pos_out = out + (g ? 12800128L : 0L);
    float* neg_out = out + (g ? 19200128L : 6400000L);

    int t = threadIdx.x;
    int wave = t >> 6, lane = t & 63;
    int i = blockIdx.x * 4 + wave;
    if (i >= NN) return;
    int j4 = lane * 4;

    half4_t sv = *(const half4_t*)(xwi + (long)i * 256 + j4);
    float a0 = (float)sv[0], a1 = (float)sv[1], a2 = (float)sv[2], a3 = (float)sv[3];
    int e0 = rp[i], e1 = rp[i + 1];
    int e = e0;
    for (; e + 8 <= e1; e += 8) {
        int s0 = col[e + 0], s1 = col[e + 1], s2 = col[e + 2], s3 = col[e + 3];
        int s4 = col[e + 4], s5 = col[e + 5], s6 = col[e + 6], s7 = col[e + 7];
        half4_t v0 = *(const half4_t*)(xwi + (long)s0 * 256 + j4);
        half4_t v1 = *(const half4_t*)(xwi + (long)s1 * 256 + j4);
        half4_t v2 = *(const half4_t*)(xwi + (long)s2 * 256 + j4);
        half4_t v3 = *(const half4_t*)(xwi + (long)s3 * 256 + j4);
        half4_t v4 = *(const half4_t*)(xwi + (long)s4 * 256 + j4);
        half4_t v5 = *(const half4_t*)(xwi + (long)s5 * 256 + j4);
        half4_t v6 = *(const half4_t*)(xwi + (long)s6 * 256 + j4);
        half4_t v7 = *(const half4_t*)(xwi + (long)s7 * 256 + j4);
        a0 += (float)v0[0] + (float)v1[0] + (float)v2[0] + (float)v3[0]
            + (float)v4[0] + (float)v5[0] + (float)v6[0] + (float)v7[0];
        a1 += (float)v0[1] + (float)v1[1] + (float)v2[1] + (float)v3[1]
            + (float)v4[1] + (float)v5[1] + (float)v6[1] + (float)v7[1];
        a2 += (float)v0[2] + (float)v1[2] + (float)v2[2] + (float)v3[2]
            + (float)v4[2] + (float)v5[2] + (float)v6[2] + (float)v7[2];
        a3 += (float)v0[3] + (float)v1[3] + (float)v2[3] + (float)v3[3]
            + (float)v4[3] + (float)v5[3] + (float)v6[3] + (float)v7[3];
    }
    for (; e + 4 <= e1; e += 4) {
        int s0 = col[e + 0], s1 = col[e + 1], s2 = col[e + 2], s3 = col[e + 3];
        half4_t v0 = *(const half4_t*)(xwi + (long)s0 * 256 + j4);
        half4_t v1 = *(const half4_t*)(xwi + (long)s1 * 256 + j4);
        half4_t v2 = *(const half4_t*)(xwi + (long)s2 * 256 + j4);
        half4_t v3 = *(const half4_t*)(xwi + (long)s3 * 256 + j4);
        a0 += (float)v0[0] + (float)v1[0] + (float)v2[0] + (float)v3[0];
        a1 += (float)v0[1] + (float)v1[1] + (float)v2[1] + (float)v3[1];
        a2 += (float)v0[2] + (float)v1[2] + (float)v2[2] + (float)v3[2];
        a3 += (float)v0[3] + (float)v1[3] + (float)v2[3] + (float)v3[3];
    }
    for (; e < e1; e++) {
        int s = col[e];
        half4_t v = *(const half4_t*)(xwi + (long)s * 256 + j4);
        a0 += (float)v[0]; a1 += (float)v[1]; a2 += (float)v[2]; a3 += (float)v[3];
    }
    float di = dinv[i];
    int jj = (lane < 32) ? j4 : (j4 - 128);
    const f32x4* bp = (const f32x4*)(bias + jj);
    f32x4 bv = *bp;
    f32x4 o;
    o[0] = fmaxf(0.f, di * a0 + bv[0]);
    o[1] = fmaxf(0.f, di * a1 + bv[1]);
    o[2] = fmaxf(0.f, di * a2 + bv[2]);
    o[3] = fmaxf(0.f, di * a3 + bv[3]);
    float* dst = ((lane < 32) ? pos_out : neg_out) + (long)i * D + jj;
    __builtin_nontemporal_store(o, (f32x4*)dst);
}

// ---------------- K6: summary mean over pos_h (separate streaming pass, ~15us) ----------------
__launch_bounds__(256)
__global__ void k_sum(const float* __restrict__ pos1, const float* __restrict__ pos2,
                      float* s1, float* s2) {
    int g = blockIdx.y;
    const float* pos = g ? pos2 : pos1;
    float* s = g ? s2 : s1;
    int t = threadIdx.x;
    int rg = t >> 5;
    int j = (t & 31) * 4;
    float4 acc = {0.f, 0.f, 0.f, 0.f};
    for (int i = blockIdx.x * 8 + rg; i < NN; i += gridDim.x * 8) {
        float4 v = *(const float4*)(pos + (long)i * D + j);
        acc.x += v.x; acc.y += v.y; acc.z += v.z; acc.w += v.w;
    }
    __shared__ float sm[8][128];
    sm[rg][j + 0] = acc.x;
    sm[rg][j + 1] = acc.y;
    sm[rg][j + 2] = acc.z;
    sm[rg][j + 3] = acc.w;
    __syncthreads();
    if (t < 128) {
        float v = 0.f;
        for (int r = 0; r < 8; r++) v += sm[r][t];
        atomicAdd(&s[t], v * (1.0f / NN));
    }
}

extern "C" void kernel_launch(void* const* d_in, const int* in_sizes, int n_in,
                              void* d_out, int out_size, void* d_ws, size_t ws_size,
                              hipStream_t stream) {
    const float* x   = (const float*)d_in[0];
    const float* W1  = (const float*)d_in[1];
    const float* b1  = (const float*)d_in[2];
    const float* W2  = (const float*)d_in[3];
    const float* b2  = (const float*)d_in[4];
    const float* mp1 = (const float*)d_in[5];
    const float* mn1 = (const float*)d_in[6];
    const float* mp2 = (const float*)d_in[7];
    const float* mn2 = (const float*)d_in[8];
    const int* e1 = (const int*)d_in[9];
    const int* e2 = (const int*)d_in[10];
    const int* perm1 = (const int*)d_in[11];
    const int* perm2 = (const int*)d_in[12];
    const int* src1 = e1;       const int* dst1 = e1 + NE;
    const int* src2 = e2;       const int* dst2 = e2 + NE;
    float* out = (float*)d_out;

    // workspace carve
    char* w = (char*)d_ws;
    _Float16* xwi1 = (_Float16*)w; w += (size_t)NN * 256 * 2;  // 25.6 MB interleaved
    _Float16* xwi2 = (_Float16*)w; w += (size_t)NN * 256 * 2;
    int* rp1 = (int*)w;   w += (size_t)(NN + 4) * 4;
    int* rp2 = (int*)w;   w += (size_t)(NN + 4) * 4;
    int* col1 = (int*)w;  w += (size_t)NE * 4;
    int* col2 = (int*)w;  w += (size_t)NE * 4;
    float* dinv1 = (float*)w; w += (size_t)NN * 4;
    float* dinv2 = (float*)w; w += (size_t)NN * 4;
    int* bcnt  = (int*)w; w += (size_t)128 * 4;
    int2* bsd1 = (int2*)w; w += (size_t)NBKT * BCAP * 8;   // 8 MB each
    int2* bsd2 = (int2*)w; w += (size_t)NBKT * BCAP * 8;
    _Float16* wt1 = (_Float16*)w; w += (size_t)D * D * 2;  // 32 KB transposed half W
    _Float16* wt2 = (_Float16*)w; w += (size_t)D * D * 2;
    int* pinv1 = (int*)w; w += (size_t)NN * 4;
    int* pinv2 = (int*)w; w += (size_t)NN * 4;

    float* s1 = out + 12800000L;
    float* s2 = out + 25600128L;
    const float* pos1 = out;
    const float* pos2 = out + 12800128L;

    k_init<<<dim3(196), 256, 0, stream>>>(s1, s2, bcnt, W1, W2, wt1, wt2,
                                          perm1, perm2, pinv1, pinv2);
    k_bucket<<<dim3(1024), 256, 0, stream>>>(src1, dst1, src2, dst2, bcnt, bsd1, bsd2);
    k_build<<<dim3(128), 512, 0, stream>>>(bcnt, bsd1, bsd2,
                                           rp1, rp2, col1, col2, dinv1, dinv2);
    k_gemm<<<dim3(GEMM_BLOCKS), 256, 0, stream>>>(wt1, wt2,
        x, mp1, mn1, mp2, mn2, pinv1, pinv2, dinv1, dinv2, xwi1, xwi2);
    k_agg<<<dim3(12500, 2), 256, 0, stream>>>(xwi1, xwi2,
                                              rp1, col1, dinv1, rp2, col2, dinv2,
                                              b1, b2, out);
    k_sum<<<dim3(128, 2), 256, 0, stream>>>(pos1, pos2, s1, s2);
}

// Round 10
// 455.416 us; speedup vs baseline: 1.0051x; 1.0051x over previous
//
#include <hip/hip_runtime.h>
#include <hip/hip_fp16.h>

#define NN 50000
#define NE 800000
#define D 128
#define GEMM_BLOCKS 3128   // 782 * 4
#define NBKT 64       // fine dst buckets per graph
#define BW 782        // bucket width (64*782 = 50048 >= NN)
#define SCAP 2048     // per-slice capacity (expected ~1563, sigma ~40)

typedef _Float16 half8_t __attribute__((ext_vector_type(8)));
typedef _Float16 half4_t __attribute__((ext_vector_type(4)));
typedef float f32x4 __attribute__((ext_vector_type(4)));

// ---------------- K0: init bcnt + summary slots + W transpose + inverse perms ----------------
__global__ void k_init(float* s1, float* s2, int* bcnt,
                       const float* __restrict__ W1, const float* __restrict__ W2,
                       _Float16* wt1, _Float16* wt2,
                       const int* __restrict__ perm1, const int* __restrict__ perm2,
                       int* pinv1, int* pinv2) {
    int i = blockIdx.x * 256 + threadIdx.x;   // grid 196*256 = 50176
    if (i < NN) { pinv1[perm1[i]] = i; pinv2[perm2[i]] = i; }
    if (i < 1024) bcnt[i] = 0;                // 2 graphs * 64 buckets * 8 slices
    if (i < D) { s1[i] = 0.f; s2[i] = 0.f; }
    if (i < 16384) {
        int n = i >> 7, k = i & 127;
        wt1[n * 128 + k] = (_Float16)W1[k * 128 + n];
        wt2[n * 128 + k] = (_Float16)W2[k * 128 + n];
    }
}

// ---------------- K1: bucket edges, cursors+storage sliced 8-way by bid&7 (XCD-local) ----------------
// Each 64B line of bsd now receives all its int2 appends from same-XCD blocks (round-robin
// dispatch), eliminating the cross-XCD partial-line ping-pong of a chip-global cursor.
// bcnt layout: [(g*64+f)*8 + slice]; bsd layout: [(f*8+slice)*SCAP + p] per graph.
__global__ void k_bucket(const int* __restrict__ src1, const int* __restrict__ dst1,
                         const int* __restrict__ src2, const int* __restrict__ dst2,
                         int* bcnt, int2* bsd1, int2* bsd2) {
    __shared__ int lcnt[128], lpos[128], gbase[128];
    int t = threadIdx.x;
    int sl = blockIdx.x & 7;              // slice = XCD bin
    if (t < 128) { lcnt[t] = 0; lpos[t] = 0; }
    __syncthreads();

    int e0 = blockIdx.x * 256 + t;
    int s1v0=0,d1v0=0,s2v0=0,d2v0=0, s1v1=0,d1v1=0,s2v1=0,d2v1=0;
    int s1v2=0,d1v2=0,s2v2=0,d2v2=0, s1v3=0,d1v3=0,s2v3=0,d2v3=0;
    bool v0 = (e0 + 0 * 262144) < NE;
    bool v1 = (e0 + 1 * 262144) < NE;
    bool v2 = (e0 + 2 * 262144) < NE;
    bool v3 = (e0 + 3 * 262144) < NE;
    if (v0) { int e = e0;             s1v0 = src1[e]; d1v0 = dst1[e]; s2v0 = src2[e]; d2v0 = dst2[e]; }
    if (v1) { int e = e0 + 262144;    s1v1 = src1[e]; d1v1 = dst1[e]; s2v1 = src2[e]; d2v1 = dst2[e]; }
    if (v2) { int e = e0 + 2*262144;  s1v2 = src1[e]; d1v2 = dst1[e]; s2v2 = src2[e]; d2v2 = dst2[e]; }
    if (v3) { int e = e0 + 3*262144;  s1v3 = src1[e]; d1v3 = dst1[e]; s2v3 = src2[e]; d2v3 = dst2[e]; }

    if (v0) { atomicAdd(&lcnt[d1v0 / BW], 1); atomicAdd(&lcnt[NBKT + d2v0 / BW], 1); }
    if (v1) { atomicAdd(&lcnt[d1v1 / BW], 1); atomicAdd(&lcnt[NBKT + d2v1 / BW], 1); }
    if (v2) { atomicAdd(&lcnt[d1v2 / BW], 1); atomicAdd(&lcnt[NBKT + d2v2 / BW], 1); }
    if (v3) { atomicAdd(&lcnt[d1v3 / BW], 1); atomicAdd(&lcnt[NBKT + d2v3 / BW], 1); }
    __syncthreads();
    if (t < 128) gbase[t] = atomicAdd(&bcnt[t * 8 + sl], lcnt[t]);
    __syncthreads();

    #define PLACE(sv, dv) { \
        int r = (dv) / BW; \
        int p = gbase[r] + atomicAdd(&lpos[r], 1); \
        if (p < SCAP) bsd1[(r * 8 + sl) * SCAP + p] = make_int2((sv), (dv)); }
    #define PLACE2(sv, dv) { \
        int r = (dv) / BW; \
        int p = gbase[NBKT + r] + atomicAdd(&lpos[NBKT + r], 1); \
        if (p < SCAP) bsd2[(r * 8 + sl) * SCAP + p] = make_int2((sv), (dv)); }
    if (v0) { PLACE(s1v0, d1v0); PLACE2(s2v0, d2v0); }
    if (v1) { PLACE(s1v1, d1v1); PLACE2(s2v1, d2v1); }
    if (v2) { PLACE(s1v2, d1v2); PLACE2(s2v2, d2v2); }
    if (v3) { PLACE(s1v3, d1v3); PLACE2(s2v3, d2v3); }
    #undef PLACE
    #undef PLACE2
}

// ---------------- K2: build CSR per bucket entirely in LDS (8 slice segments) ----------------
__launch_bounds__(512)
__global__ void k_build(const int* __restrict__ bcnt,
                        const int2* __restrict__ bsd1, const int2* __restrict__ bsd2,
                        int* rp1, int* rp2, int* col1, int* col2,
                        float* dinv1, float* dinv2) {
    __shared__ int h[1024];
    __shared__ int tsum[512];
    __shared__ int tb[64];
    __shared__ int ns[8];
    __shared__ int bbase;
    int t = threadIdx.x;
    int g = blockIdx.x >> 6;         // graph
    int f = blockIdx.x & 63;         // bucket
    const int2* bsd = (g ? bsd2 : bsd1) + f * 8 * SCAP;
    int* rp = g ? rp2 : rp1;
    int* col = g ? col2 : col1;
    float* dinv = g ? dinv2 : dinv1;

    h[t] = 0; h[t + 512] = 0;
    if (t < 8) {
        int v = bcnt[(g * NBKT + f) * 8 + t];
        ns[t] = (v > SCAP) ? SCAP : v;
    }
    if (t < NBKT) {
        int tot = 0;
        #pragma unroll
        for (int s = 0; s < 8; s++) tot += bcnt[(g * NBKT + t) * 8 + s];
        tb[t] = tot;
    }
    __syncthreads();

    #pragma unroll
    for (int s = 0; s < 8; s++) {
        int n = ns[s];
        const int2* seg = bsd + s * SCAP;
        for (int i = t; i < n; i += 512) atomicAdd(&h[seg[i].y - f * BW], 1);
    }
    __syncthreads();
    if (t == 0) { int b = 0; for (int j = 0; j < f; j++) b += tb[j]; bbase = b; }

    int a0 = h[2 * t], a1 = h[2 * t + 1];
    int s = a0 + a1;
    tsum[t] = s;
    __syncthreads();
    for (int off = 1; off < 512; off <<= 1) {
        int add = (t >= off) ? tsum[t - off] : 0;
        __syncthreads();
        tsum[t] += add;
        __syncthreads();
    }
    int excl = tsum[t] - s + bbase;
    int idx = 2 * t, gd = f * BW + idx;
    int e0 = excl, e1 = excl + a0;
    h[2 * t] = e0; h[2 * t + 1] = e1;     // histogram slots become absolute cursors
    if (idx < BW && gd < NN)         { rp[gd]     = e0; dinv[gd]     = rsqrtf((float)(a0 + 1)); }
    if (idx + 1 < BW && gd + 1 < NN) { rp[gd + 1] = e1; dinv[gd + 1] = rsqrtf((float)(a1 + 1)); }
    if (f == 63 && t == 0) rp[NN] = NE;
    __syncthreads();

    #pragma unroll
    for (int sg = 0; sg < 8; sg++) {
        int n = ns[sg];
        const int2* seg = bsd + sg * SCAP;
        for (int i = t; i < n; i += 512) {
            int2 e = seg[i];
            int p = atomicAdd(&h[e.y - f * BW], 1);   // LDS cursor
            col[p] = e.x;
        }
    }
}

// ---------------- K3: 4 GEMMs, all branches stream x/mask in NATURAL order ----------------
__launch_bounds__(256)
__global__ void k_gemm(const _Float16* __restrict__ wt1, const _Float16* __restrict__ wt2,
                       const float* __restrict__ x,
                       const float* __restrict__ mp1, const float* __restrict__ mn1,
                       const float* __restrict__ mp2, const float* __restrict__ mn2,
                       const int* __restrict__ pinv1, const int* __restrict__ pinv2,
                       const float* __restrict__ dinv1, const float* __restrict__ dinv2,
                       _Float16* xwi1, _Float16* xwi2) {
    __shared__ __align__(16) _Float16 ST[4][16][136];   // per-wave private transpose scratch

    int g = blockIdx.x;                    // 0..3127
    int which = g / 782;                   // 0 = pos1, 1 = neg1, 2 = pos2, 3 = neg2
    int bx = g - which * 782;
    const _Float16* wt = (which < 2) ? wt1 : wt2;
    const float* mask = (which == 0) ? mp1 : (which == 1) ? mn1 : (which == 2) ? mp2 : mn2;
    const int* pinv = (which == 1) ? pinv1 : (which == 3) ? pinv2 : nullptr;
    const float* dinv = (which < 2) ? dinv1 : dinv2;
    _Float16* out = ((which < 2) ? xwi1 : xwi2) + ((which & 1) ? 128 : 0);

    int t = threadIdx.x;
    int wave = t >> 6;
    int lane = t & 63;
    int quad = lane >> 4;
    int m = lane & 15;
    int tile = bx * 4 + wave;
    if (tile * 16 >= NN) return;           // no barriers -> safe early return

    int row = tile * 16 + m;               // natural compute row (streaming reads)
    const float* xrow = x + (long)row * D;
    const float* mrow = mask + (long)row * D;

    half8_t a[4];
    #pragma unroll
    for (int kk = 0; kk < 4; kk++) {
        int k0 = kk * 32 + quad * 8;
        f32x4 xa = *(const f32x4*)(xrow + k0);
        f32x4 xb = *(const f32x4*)(xrow + k0 + 4);
        f32x4 ma = __builtin_nontemporal_load((const f32x4*)(mrow + k0));
        f32x4 mb = __builtin_nontemporal_load((const f32x4*)(mrow + k0 + 4));
        a[kk][0] = (_Float16)(xa[0] * ma[0]);
        a[kk][1] = (_Float16)(xa[1] * ma[1]);
        a[kk][2] = (_Float16)(xa[2] * ma[2]);
        a[kk][3] = (_Float16)(xa[3] * ma[3]);
        a[kk][4] = (_Float16)(xb[0] * mb[0]);
        a[kk][5] = (_Float16)(xb[1] * mb[1]);
        a[kk][6] = (_Float16)(xb[2] * mb[2]);
        a[kk][7] = (_Float16)(xb[3] * mb[3]);
    }

    // Swapped operands: A = W-fragment (out-col), B = x-fragment (x-row).
    f32x4 accs[8];
    #pragma unroll
    for (int nt = 0; nt < 8; nt++) {
        const _Float16* wrow = wt + (nt * 16 + m) * 128 + quad * 8;
        f32x4 acc = {0.f, 0.f, 0.f, 0.f};
        #pragma unroll
        for (int kk = 0; kk < 4; kk++) {
            half8_t w = *(const half8_t*)(wrow + kk * 32);
            acc = __builtin_amdgcn_mfma_f32_16x16x32_f16(w, a[kk], acc, 0, 0, 0);
        }
        accs[nt] = acc;
    }

    // Output row: natural for pos, pinv-scattered for neg.
    int orow = pinv ? pinv[row] : row;
    float ds = dinv[orow];
    _Float16* st = &ST[wave][0][0];

    #pragma unroll
    for (int nt = 0; nt < 8; nt++) {
        half4_t h;
        h[0] = (_Float16)(accs[nt][0] * ds);
        h[1] = (_Float16)(accs[nt][1] * ds);
        h[2] = (_Float16)(accs[nt][2] * ds);
        h[3] = (_Float16)(accs[nt][3] * ds);
        *(half4_t*)(st + m * 136 + nt * 16 + quad * 4) = h;
    }
    // Read back row-contiguous: each lane stores 16B chunks of ITS row orow.
    #pragma unroll
    for (int p = 0; p < 4; p++) {
        int cc = (lane >> 4) + p * 4;       // 16B chunk index 0..15
        half8_t v = *(const half8_t*)(st + m * 136 + cc * 8);
        *(half8_t*)(out + (long)orow * 256 + cc * 8) = v;
    }
}

// ---------------- K5: CSR gather aggregation + bias + ReLU (no atomics, no barrier) ----------------
__launch_bounds__(256)
__global__ void k_agg(const _Float16* __restrict__ xwi1, const _Float16* __restrict__ xwi2,
                      const int* __restrict__ rp1, const int* __restrict__ col1,
                      const float* __restrict__ dinv1,
                      const int* __restrict__ rp2, const int* __restrict__ col2,
                      const float* __restrict__ dinv2,
                      const float* __restrict__ b1, const float* __restrict__ b2,
                      float* out) {
    int g = blockIdx.y;
    const _Float16* xwi = g ? xwi2 : xwi1;
    const int* rp = g ? rp2 : rp1;
    const int* col = g ? col2 : col1;
    const float* dinv = g ? dinv2 : dinv1;
    const float* bias = g ? b2 : b1;
    float* pos_out = out + (g ? 12800128L : 0L);
    float* neg_out = out + (g ? 19200128L : 6400000L);

    int t = threadIdx.x;
    int wave = t >> 6, lane = t & 63;
    int i = blockIdx.x * 4 + wave;
    if (i >= NN) return;
    int j4 = lane * 4;

    half4_t sv = *(const half4_t*)(xwi + (long)i * 256 + j4);
    float a0 = (float)sv[0], a1 = (float)sv[1], a2 = (float)sv[2], a3 = (float)sv[3];
    int e0 = rp[i], e1 = rp[i + 1];
    int e = e0;
    for (; e + 8 <= e1; e += 8) {
        int s0 = col[e + 0], s1 = col[e + 1], s2 = col[e + 2], s3 = col[e + 3];
        int s4 = col[e + 4], s5 = col[e + 5], s6 = col[e + 6], s7 = col[e + 7];
        half4_t v0 = *(const half4_t*)(xwi + (long)s0 * 256 + j4);
        half4_t v1 = *(const half4_t*)(xwi + (long)s1 * 256 + j4);
        half4_t v2 = *(const half4_t*)(xwi + (long)s2 * 256 + j4);
        half4_t v3 = *(const half4_t*)(xwi + (long)s3 * 256 + j4);
        half4_t v4 = *(const half4_t*)(xwi + (long)s4 * 256 + j4);
        half4_t v5 = *(const half4_t*)(xwi + (long)s5 * 256 + j4);
        half4_t v6 = *(const half4_t*)(xwi + (long)s6 * 256 + j4);
        half4_t v7 = *(const half4_t*)(xwi + (long)s7 * 256 + j4);
        a0 += (float)v0[0] + (float)v1[0] + (float)v2[0] + (float)v3[0]
            + (float)v4[0] + (float)v5[0] + (float)v6[0] + (float)v7[0];
        a1 += (float)v0[1] + (float)v1[1] + (float)v2[1] + (float)v3[1]
            + (float)v4[1] + (float)v5[1] + (float)v6[1] + (float)v7[1];
        a2 += (float)v0[2] + (float)v1[2] + (float)v2[2] + (float)v3[2]
            + (float)v4[2] + (float)v5[2] + (float)v6[2] + (float)v7[2];
        a3 += (float)v0[3] + (float)v1[3] + (float)v2[3] + (float)v3[3]
            + (float)v4[3] + (float)v5[3] + (float)v6[3] + (float)v7[3];
    }
    for (; e + 4 <= e1; e += 4) {
        int s0 = col[e + 0], s1 = col[e + 1], s2 = col[e + 2], s3 = col[e + 3];
        half4_t v0 = *(const half4_t*)(xwi + (long)s0 * 256 + j4);
        half4_t v1 = *(const half4_t*)(xwi + (long)s1 * 256 + j4);
        half4_t v2 = *(const half4_t*)(xwi + (long)s2 * 256 + j4);
        half4_t v3 = *(const half4_t*)(xwi + (long)s3 * 256 + j4);
        a0 += (float)v0[0] + (float)v1[0] + (float)v2[0] + (float)v3[0];
        a1 += (float)v0[1] + (float)v1[1] + (float)v2[1] + (float)v3[1];
        a2 += (float)v0[2] + (float)v1[2] + (float)v2[2] + (float)v3[2];
        a3 += (float)v0[3] + (float)v1[3] + (float)v2[3] + (float)v3[3];
    }
    for (; e < e1; e++) {
        int s = col[e];
        half4_t v = *(const half4_t*)(xwi + (long)s * 256 + j4);
        a0 += (float)v[0]; a1 += (float)v[1]; a2 += (float)v[2]; a3 += (float)v[3];
    }
    float di = dinv[i];
    int jj = (lane < 32) ? j4 : (j4 - 128);
    const f32x4* bp = (const f32x4*)(bias + jj);
    f32x4 bv = *bp;
    f32x4 o;
    o[0] = fmaxf(0.f, di * a0 + bv[0]);
    o[1] = fmaxf(0.f, di * a1 + bv[1]);
    o[2] = fmaxf(0.f, di * a2 + bv[2]);
    o[3] = fmaxf(0.f, di * a3 + bv[3]);
    float* dst = ((lane < 32) ? pos_out : neg_out) + (long)i * D + jj;
    __builtin_nontemporal_store(o, (f32x4*)dst);
}

// ---------------- K6: summary mean over pos_h (512 blocks/graph, nontemporal) ----------------
__launch_bounds__(256)
__global__ void k_sum(const float* __restrict__ pos1, const float* __restrict__ pos2,
                      float* s1, float* s2) {
    int g = blockIdx.y;
    const float* pos = g ? pos2 : pos1;
    float* s = g ? s2 : s1;
    int t = threadIdx.x;
    int rg = t >> 5;
    int j = (t & 31) * 4;
    f32x4 acc = {0.f, 0.f, 0.f, 0.f};
    for (int i = blockIdx.x * 8 + rg; i < NN; i += gridDim.x * 8) {
        f32x4 v = __builtin_nontemporal_load((const f32x4*)(pos + (long)i * D + j));
        acc[0] += v[0]; acc[1] += v[1]; acc[2] += v[2]; acc[3] += v[3];
    }
    __shared__ float sm[8][128];
    sm[rg][j + 0] = acc[0];
    sm[rg][j + 1] = acc[1];
    sm[rg][j + 2] = acc[2];
    sm[rg][j + 3] = acc[3];
    __syncthreads();
    if (t < 128) {
        float v = 0.f;
        for (int r = 0; r < 8; r++) v += sm[r][t];
        atomicAdd(&s[t], v * (1.0f / NN));
    }
}

extern "C" void kernel_launch(void* const* d_in, const int* in_sizes, int n_in,
                              void* d_out, int out_size, void* d_ws, size_t ws_size,
                              hipStream_t stream) {
    const float* x   = (const float*)d_in[0];
    const float* W1  = (const float*)d_in[1];
    const float* b1  = (const float*)d_in[2];
    const float* W2  = (const float*)d_in[3];
    const float* b2  = (const float*)d_in[4];
    const float* mp1 = (const float*)d_in[5];
    const float* mn1 = (const float*)d_in[6];
    const float* mp2 = (const float*)d_in[7];
    const float* mn2 = (const float*)d_in[8];
    const int* e1 = (const int*)d_in[9];
    const int* e2 = (const int*)d_in[10];
    const int* perm1 = (const int*)d_in[11];
    const int* perm2 = (const int*)d_in[12];
    const int* src1 = e1;       const int* dst1 = e1 + NE;
    const int* src2 = e2;       const int* dst2 = e2 + NE;
    float* out = (float*)d_out;

    // workspace carve
    char* w = (char*)d_ws;
    _Float16* xwi1 = (_Float16*)w; w += (size_t)NN * 256 * 2;  // 25.6 MB interleaved
    _Float16* xwi2 = (_Float16*)w; w += (size_t)NN * 256 * 2;
    int* rp1 = (int*)w;   w += (size_t)(NN + 4) * 4;
    int* rp2 = (int*)w;   w += (size_t)(NN + 4) * 4;
    int* col1 = (int*)w;  w += (size_t)NE * 4;
    int* col2 = (int*)w;  w += (size_t)NE * 4;
    float* dinv1 = (float*)w; w += (size_t)NN * 4;
    float* dinv2 = (float*)w; w += (size_t)NN * 4;
    int* bcnt  = (int*)w; w += (size_t)1024 * 4;
    int2* bsd1 = (int2*)w; w += (size_t)NBKT * 8 * SCAP * 8;   // 8 MB each
    int2* bsd2 = (int2*)w; w += (size_t)NBKT * 8 * SCAP * 8;
    _Float16* wt1 = (_Float16*)w; w += (size_t)D * D * 2;  // 32 KB transposed half W
    _Float16* wt2 = (_Float16*)w; w += (size_t)D * D * 2;
    int* pinv1 = (int*)w; w += (size_t)NN * 4;
    int* pinv2 = (int*)w; w += (size_t)NN * 4;

    float* s1 = out + 12800000L;
    float* s2 = out + 25600128L;
    const float* pos1 = out;
    const float* pos2 = out + 12800128L;

    k_init<<<dim3(196), 256, 0, stream>>>(s1, s2, bcnt, W1, W2, wt1, wt2,
                                          perm1, perm2, pinv1, pinv2);
    k_bucket<<<dim3(1024), 256, 0, stream>>>(src1, dst1, src2, dst2, bcnt, bsd1, bsd2);
    k_build<<<dim3(128), 512, 0, stream>>>(bcnt, bsd1, bsd2,
                                           rp1, rp2, col1, col2, dinv1, dinv2);
    k_gemm<<<dim3(GEMM_BLOCKS), 256, 0, stream>>>(wt1, wt2,
        x, mp1, mn1, mp2, mn2, pinv1, pinv2, dinv1, dinv2, xwi1, xwi2);
    k_agg<<<dim3(12500, 2), 256, 0, stream>>>(xwi1, xwi2,
                                              rp1, col1, dinv1, rp2, col2, dinv2,
                                              b1, b2, out);
    k_sum<<<dim3(512, 2), 256, 0, stream>>>(pos1, pos2, s1, s2);
}

// Round 11
// 454.710 us; speedup vs baseline: 1.0067x; 1.0016x over previous
//
#include <hip/hip_runtime.h>
#include <hip/hip_fp16.h>

#define NN 50000
#define NE 800000
#define D 128
#define BKT_BLOCKS 1024
#define GEMM_BLOCKS 3128   // 782 * 4
#define NBKT 64       // fine dst buckets per graph
#define BW 782        // bucket width (64*782 = 50048 >= NN)
#define SCAP 2048     // per-slice capacity (expected ~1563, sigma ~40)

typedef _Float16 half8_t __attribute__((ext_vector_type(8)));
typedef _Float16 half4_t __attribute__((ext_vector_type(4)));
typedef float f32x4 __attribute__((ext_vector_type(4)));

// ---------------- K0: init bcnt + summary slots + W transpose + inverse perms ----------------
__global__ void k_init(float* s1, float* s2, int* bcnt,
                       const float* __restrict__ W1, const float* __restrict__ W2,
                       _Float16* wt1, _Float16* wt2,
                       const int* __restrict__ perm1, const int* __restrict__ perm2,
                       int* pinv1, int* pinv2) {
    int i = blockIdx.x * 256 + threadIdx.x;   // grid 196*256 = 50176
    if (i < NN) { pinv1[perm1[i]] = i; pinv2[perm2[i]] = i; }
    if (i < 1024) bcnt[i] = 0;                // 2 graphs * 64 buckets * 8 slices
    if (i < D) { s1[i] = 0.f; s2[i] = 0.f; }
    if (i < 16384) {
        int n = i >> 7, k = i & 127;
        wt1[n * 128 + k] = (_Float16)W1[k * 128 + n];
        wt2[n * 128 + k] = (_Float16)W2[k * 128 + n];
    }
}

// ---------------- K1: MERGED bucket (blocks 0..1023) + 4 GEMMs (blocks 1024..4151) ----------------
// bucket -> build -> agg and init -> gemm -> agg are independent chains; dinv scaling moved
// to k_agg so gemm no longer needs the CSR build. Merging hides bucket's ~35us entirely
// under gemm and removes one launch boundary. Both halves are streaming workloads (no
// shared atomic working set -> R1's thrash mode absent).
__launch_bounds__(256)
__global__ void k_bucket_gemm(const int* __restrict__ src1, const int* __restrict__ dst1,
                              const int* __restrict__ src2, const int* __restrict__ dst2,
                              int* bcnt, int2* bsd1, int2* bsd2,
                              const _Float16* __restrict__ wt1, const _Float16* __restrict__ wt2,
                              const float* __restrict__ x,
                              const float* __restrict__ mp1, const float* __restrict__ mn1,
                              const float* __restrict__ mp2, const float* __restrict__ mn2,
                              const int* __restrict__ pinv1, const int* __restrict__ pinv2,
                              _Float16* xwi1, _Float16* xwi2) {
    __shared__ int lcnt[128], lpos[128], gbase[128];
    __shared__ __align__(16) _Float16 ST[4][16][136];   // per-wave private transpose scratch
    int t = threadIdx.x;
    int bid = blockIdx.x;

    if (bid < BKT_BLOCKS) {
        // ---- BUCKET block (XCD-sliced cursors, R10 body) ----
        int sl = bid & 7;              // slice = XCD bin
        if (t < 128) { lcnt[t] = 0; lpos[t] = 0; }
        __syncthreads();

        int e0 = bid * 256 + t;
        int s1v0=0,d1v0=0,s2v0=0,d2v0=0, s1v1=0,d1v1=0,s2v1=0,d2v1=0;
        int s1v2=0,d1v2=0,s2v2=0,d2v2=0, s1v3=0,d1v3=0,s2v3=0,d2v3=0;
        bool v0 = (e0 + 0 * 262144) < NE;
        bool v1 = (e0 + 1 * 262144) < NE;
        bool v2 = (e0 + 2 * 262144) < NE;
        bool v3 = (e0 + 3 * 262144) < NE;
        if (v0) { int e = e0;             s1v0 = src1[e]; d1v0 = dst1[e]; s2v0 = src2[e]; d2v0 = dst2[e]; }
        if (v1) { int e = e0 + 262144;    s1v1 = src1[e]; d1v1 = dst1[e]; s2v1 = src2[e]; d2v1 = dst2[e]; }
        if (v2) { int e = e0 + 2*262144;  s1v2 = src1[e]; d1v2 = dst1[e]; s2v2 = src2[e]; d2v2 = dst2[e]; }
        if (v3) { int e = e0 + 3*262144;  s1v3 = src1[e]; d1v3 = dst1[e]; s2v3 = src2[e]; d2v3 = dst2[e]; }

        if (v0) { atomicAdd(&lcnt[d1v0 / BW], 1); atomicAdd(&lcnt[NBKT + d2v0 / BW], 1); }
        if (v1) { atomicAdd(&lcnt[d1v1 / BW], 1); atomicAdd(&lcnt[NBKT + d2v1 / BW], 1); }
        if (v2) { atomicAdd(&lcnt[d1v2 / BW], 1); atomicAdd(&lcnt[NBKT + d2v2 / BW], 1); }
        if (v3) { atomicAdd(&lcnt[d1v3 / BW], 1); atomicAdd(&lcnt[NBKT + d2v3 / BW], 1); }
        __syncthreads();
        if (t < 128) gbase[t] = atomicAdd(&bcnt[t * 8 + sl], lcnt[t]);
        __syncthreads();

        #define PLACE(sv, dv) { \
            int r = (dv) / BW; \
            int p = gbase[r] + atomicAdd(&lpos[r], 1); \
            if (p < SCAP) bsd1[(r * 8 + sl) * SCAP + p] = make_int2((sv), (dv)); }
        #define PLACE2(sv, dv) { \
            int r = (dv) / BW; \
            int p = gbase[NBKT + r] + atomicAdd(&lpos[NBKT + r], 1); \
            if (p < SCAP) bsd2[(r * 8 + sl) * SCAP + p] = make_int2((sv), (dv)); }
        if (v0) { PLACE(s1v0, d1v0); PLACE2(s2v0, d2v0); }
        if (v1) { PLACE(s1v1, d1v1); PLACE2(s2v1, d2v1); }
        if (v2) { PLACE(s1v2, d1v2); PLACE2(s2v2, d2v2); }
        if (v3) { PLACE(s1v3, d1v3); PLACE2(s2v3, d2v3); }
        #undef PLACE
        #undef PLACE2
        return;
    }

    // ---- GEMM block: natural-order streaming, RAW xw output (dinv applied in k_agg) ----
    int g = bid - BKT_BLOCKS;              // 0..3127
    int which = g / 782;                   // 0 = pos1, 1 = neg1, 2 = pos2, 3 = neg2
    int bx = g - which * 782;
    const _Float16* wt = (which < 2) ? wt1 : wt2;
    const float* mask = (which == 0) ? mp1 : (which == 1) ? mn1 : (which == 2) ? mp2 : mn2;
    const int* pinv = (which == 1) ? pinv1 : (which == 3) ? pinv2 : nullptr;
    _Float16* out = ((which < 2) ? xwi1 : xwi2) + ((which & 1) ? 128 : 0);

    int wave = t >> 6;
    int lane = t & 63;
    int quad = lane >> 4;
    int m = lane & 15;
    int tile = bx * 4 + wave;
    if (tile * 16 >= NN) return;           // no barriers in this path -> safe early return

    int row = tile * 16 + m;               // natural compute row (streaming reads)
    const float* xrow = x + (long)row * D;
    const float* mrow = mask + (long)row * D;

    half8_t a[4];
    #pragma unroll
    for (int kk = 0; kk < 4; kk++) {
        int k0 = kk * 32 + quad * 8;
        f32x4 xa = *(const f32x4*)(xrow + k0);
        f32x4 xb = *(const f32x4*)(xrow + k0 + 4);
        f32x4 ma = __builtin_nontemporal_load((const f32x4*)(mrow + k0));
        f32x4 mb = __builtin_nontemporal_load((const f32x4*)(mrow + k0 + 4));
        a[kk][0] = (_Float16)(xa[0] * ma[0]);
        a[kk][1] = (_Float16)(xa[1] * ma[1]);
        a[kk][2] = (_Float16)(xa[2] * ma[2]);
        a[kk][3] = (_Float16)(xa[3] * ma[3]);
        a[kk][4] = (_Float16)(xb[0] * mb[0]);
        a[kk][5] = (_Float16)(xb[1] * mb[1]);
        a[kk][6] = (_Float16)(xb[2] * mb[2]);
        a[kk][7] = (_Float16)(xb[3] * mb[3]);
    }

    // Swapped operands: A = W-fragment (out-col), B = x-fragment (x-row).
    f32x4 accs[8];
    #pragma unroll
    for (int nt = 0; nt < 8; nt++) {
        const _Float16* wrow = wt + (nt * 16 + m) * 128 + quad * 8;
        f32x4 acc = {0.f, 0.f, 0.f, 0.f};
        #pragma unroll
        for (int kk = 0; kk < 4; kk++) {
            half8_t w = *(const half8_t*)(wrow + kk * 32);
            acc = __builtin_amdgcn_mfma_f32_16x16x32_f16(w, a[kk], acc, 0, 0, 0);
        }
        accs[nt] = acc;
    }

    // Output row: natural for pos, pinv-scattered for neg. NO dinv scale here.
    int orow = pinv ? pinv[row] : row;
    _Float16* st = &ST[wave][0][0];

    #pragma unroll
    for (int nt = 0; nt < 8; nt++) {
        half4_t h;
        h[0] = (_Float16)accs[nt][0];
        h[1] = (_Float16)accs[nt][1];
        h[2] = (_Float16)accs[nt][2];
        h[3] = (_Float16)accs[nt][3];
        *(half4_t*)(st + m * 136 + nt * 16 + quad * 4) = h;
    }
    // Read back row-contiguous: each lane stores 16B chunks of ITS row orow.
    #pragma unroll
    for (int p = 0; p < 4; p++) {
        int cc = (lane >> 4) + p * 4;       // 16B chunk index 0..15
        half8_t v = *(const half8_t*)(st + m * 136 + cc * 8);
        *(half8_t*)(out + (long)orow * 256 + cc * 8) = v;
    }
}

// ---------------- K2: build CSR per bucket entirely in LDS (8 slice segments) ----------------
__launch_bounds__(512)
__global__ void k_build(const int* __restrict__ bcnt,
                        const int2* __restrict__ bsd1, const int2* __restrict__ bsd2,
                        int* rp1, int* rp2, int* col1, int* col2,
                        float* dinv1, float* dinv2) {
    __shared__ int h[1024];
    __shared__ int tsum[512];
    __shared__ int tb[64];
    __shared__ int ns[8];
    __shared__ int bbase;
    int t = threadIdx.x;
    int g = blockIdx.x >> 6;         // graph
    int f = blockIdx.x & 63;         // bucket
    const int2* bsd = (g ? bsd2 : bsd1) + f * 8 * SCAP;
    int* rp = g ? rp2 : rp1;
    int* col = g ? col2 : col1;
    float* dinv = g ? dinv2 : dinv1;

    h[t] = 0; h[t + 512] = 0;
    if (t < 8) {
        int v = bcnt[(g * NBKT + f) * 8 + t];
        ns[t] = (v > SCAP) ? SCAP : v;
    }
    if (t < NBKT) {
        int tot = 0;
        #pragma unroll
        for (int s = 0; s < 8; s++) tot += bcnt[(g * NBKT + t) * 8 + s];
        tb[t] = tot;
    }
    __syncthreads();

    #pragma unroll
    for (int s = 0; s < 8; s++) {
        int n = ns[s];
        const int2* seg = bsd + s * SCAP;
        for (int i = t; i < n; i += 512) atomicAdd(&h[seg[i].y - f * BW], 1);
    }
    __syncthreads();
    if (t == 0) { int b = 0; for (int j = 0; j < f; j++) b += tb[j]; bbase = b; }

    int a0 = h[2 * t], a1 = h[2 * t + 1];
    int s = a0 + a1;
    tsum[t] = s;
    __syncthreads();
    for (int off = 1; off < 512; off <<= 1) {
        int add = (t >= off) ? tsum[t - off] : 0;
        __syncthreads();
        tsum[t] += add;
        __syncthreads();
    }
    int excl = tsum[t] - s + bbase;
    int idx = 2 * t, gd = f * BW + idx;
    int e0 = excl, e1 = excl + a0;
    h[2 * t] = e0; h[2 * t + 1] = e1;     // histogram slots become absolute cursors
    if (idx < BW && gd < NN)         { rp[gd]     = e0; dinv[gd]     = rsqrtf((float)(a0 + 1)); }
    if (idx + 1 < BW && gd + 1 < NN) { rp[gd + 1] = e1; dinv[gd + 1] = rsqrtf((float)(a1 + 1)); }
    if (f == 63 && t == 0) rp[NN] = NE;
    __syncthreads();

    #pragma unroll
    for (int sg = 0; sg < 8; sg++) {
        int n = ns[sg];
        const int2* seg = bsd + sg * SCAP;
        for (int i = t; i < n; i += 512) {
            int2 e = seg[i];
            int p = atomicAdd(&h[e.y - f * BW], 1);   // LDS cursor
            col[p] = e.x;
        }
    }
}

// ---------------- K5: CSR gather aggregation with per-edge dinv[s] + bias + ReLU ----------------
// out[i] = relu(dinv[i] * (dinv[i]*xw[i] + sum_s dinv[s]*xw[s]) + bias)
__launch_bounds__(256)
__global__ void k_agg(const _Float16* __restrict__ xwi1, const _Float16* __restrict__ xwi2,
                      const int* __restrict__ rp1, const int* __restrict__ col1,
                      const float* __restrict__ dinv1,
                      const int* __restrict__ rp2, const int* __restrict__ col2,
                      const float* __restrict__ dinv2,
                      const float* __restrict__ b1, const float* __restrict__ b2,
                      float* out) {
    int g = blockIdx.y;
    const _Float16* xwi = g ? xwi2 : xwi1;
    const int* rp = g ? rp2 : rp1;
    const int* col = g ? col2 : col1;
    const float* dinv = g ? dinv2 : dinv1;
    const float* bias = g ? b2 : b1;
    float* pos_out = out + (g ? 12800128L : 0L);
    float* neg_out = out + (g ? 19200128L : 6400000L);

    int t = threadIdx.x;
    int wave = t >> 6, lane = t & 63;
    int i = blockIdx.x * 4 + wave;
    if (i >= NN) return;
    int j4 = lane * 4;

    float di = dinv[i];
    half4_t sv = *(const half4_t*)(xwi + (long)i * 256 + j4);
    float a0 = di * (float)sv[0], a1 = di * (float)sv[1];
    float a2 = di * (float)sv[2], a3 = di * (float)sv[3];
    int e0 = rp[i], e1 = rp[i + 1];
    int e = e0;
    for (; e + 8 <= e1; e += 8) {
        int s0 = col[e + 0], s1 = col[e + 1], s2 = col[e + 2], s3 = col[e + 3];
        int s4 = col[e + 4], s5 = col[e + 5], s6 = col[e + 6], s7 = col[e + 7];
        float ds0 = dinv[s0], ds1 = dinv[s1], ds2 = dinv[s2], ds3 = dinv[s3];
        float ds4 = dinv[s4], ds5 = dinv[s5], ds6 = dinv[s6], ds7 = dinv[s7];
        half4_t v0 = *(const half4_t*)(xwi + (long)s0 * 256 + j4);
        half4_t v1 = *(const half4_t*)(xwi + (long)s1 * 256 + j4);
        half4_t v2 = *(const half4_t*)(xwi + (long)s2 * 256 + j4);
        half4_t v3 = *(const half4_t*)(xwi + (long)s3 * 256 + j4);
        half4_t v4 = *(const half4_t*)(xwi + (long)s4 * 256 + j4);
        half4_t v5 = *(const half4_t*)(xwi + (long)s5 * 256 + j4);
        half4_t v6 = *(const half4_t*)(xwi + (long)s6 * 256 + j4);
        half4_t v7 = *(const half4_t*)(xwi + (long)s7 * 256 + j4);
        a0 += ds0*(float)v0[0] + ds1*(float)v1[0] + ds2*(float)v2[0] + ds3*(float)v3[0]
            + ds4*(float)v4[0] + ds5*(float)v5[0] + ds6*(float)v6[0] + ds7*(float)v7[0];
        a1 += ds0*(float)v0[1] + ds1*(float)v1[1] + ds2*(float)v2[1] + ds3*(float)v3[1]
            + ds4*(float)v4[1] + ds5*(float)v5[1] + ds6*(float)v6[1] + ds7*(float)v7[1];
        a2 += ds0*(float)v0[2] + ds1*(float)v1[2] + ds2*(float)v2[2] + ds3*(float)v3[2]
            + ds4*(float)v4[2] + ds5*(float)v5[2] + ds6*(float)v6[2] + ds7*(float)v7[2];
        a3 += ds0*(float)v0[3] + ds1*(float)v1[3] + ds2*(float)v2[3] + ds3*(float)v3[3]
            + ds4*(float)v4[3] + ds5*(float)v5[3] + ds6*(float)v6[3] + ds7*(float)v7[3];
    }
    for (; e + 4 <= e1; e += 4) {
        int s0 = col[e + 0], s1 = col[e + 1], s2 = col[e + 2], s3 = col[e + 3];
        float ds0 = dinv[s0], ds1 = dinv[s1], ds2 = dinv[s2], ds3 = dinv[s3];
        half4_t v0 = *(const half4_t*)(xwi + (long)s0 * 256 + j4);
        half4_t v1 = *(const half4_t*)(xwi + (long)s1 * 256 + j4);
        half4_t v2 = *(const half4_t*)(xwi + (long)s2 * 256 + j4);
        half4_t v3 = *(const half4_t*)(xwi + (long)s3 * 256 + j4);
        a0 += ds0*(float)v0[0] + ds1*(float)v1[0] + ds2*(float)v2[0] + ds3*(float)v3[0];
        a1 += ds0*(float)v0[1] + ds1*(float)v1[1] + ds2*(float)v2[1] + ds3*(float)v3[1];
        a2 += ds0*(float)v0[2] + ds1*(float)v1[2] + ds2*(float)v2[2] + ds3*(float)v3[2];
        a3 += ds0*(float)v0[3] + ds1*(float)v1[3] + ds2*(float)v2[3] + ds3*(float)v3[3];
    }
    for (; e < e1; e++) {
        int s = col[e];
        float ds = dinv[s];
        half4_t v = *(const half4_t*)(xwi + (long)s * 256 + j4);
        a0 += ds*(float)v[0]; a1 += ds*(float)v[1]; a2 += ds*(float)v[2]; a3 += ds*(float)v[3];
    }
    int jj = (lane < 32) ? j4 : (j4 - 128);
    const f32x4* bp = (const f32x4*)(bias + jj);
    f32x4 bv = *bp;
    f32x4 o;
    o[0] = fmaxf(0.f, di * a0 + bv[0]);
    o[1] = fmaxf(0.f, di * a1 + bv[1]);
    o[2] = fmaxf(0.f, di * a2 + bv[2]);
    o[3] = fmaxf(0.f, di * a3 + bv[3]);
    float* dst = ((lane < 32) ? pos_out : neg_out) + (long)i * D + jj;
    __builtin_nontemporal_store(o, (f32x4*)dst);
}

// ---------------- K6: summary mean over pos_h (512 blocks/graph, nontemporal) ----------------
__launch_bounds__(256)
__global__ void k_sum(const float* __restrict__ pos1, const float* __restrict__ pos2,
                      float* s1, float* s2) {
    int g = blockIdx.y;
    const float* pos = g ? pos2 : pos1;
    float* s = g ? s2 : s1;
    int t = threadIdx.x;
    int rg = t >> 5;
    int j = (t & 31) * 4;
    f32x4 acc = {0.f, 0.f, 0.f, 0.f};
    for (int i = blockIdx.x * 8 + rg; i < NN; i += gridDim.x * 8) {
        f32x4 v = __builtin_nontemporal_load((const f32x4*)(pos + (long)i * D + j));
        acc[0] += v[0]; acc[1] += v[1]; acc[2] += v[2]; acc[3] += v[3];
    }
    __shared__ float sm[8][128];
    sm[rg][j + 0] = acc[0];
    sm[rg][j + 1] = acc[1];
    sm[rg][j + 2] = acc[2];
    sm[rg][j + 3] = acc[3];
    __syncthreads();
    if (t < 128) {
        float v = 0.f;
        for (int r = 0; r < 8; r++) v += sm[r][t];
        atomicAdd(&s[t], v * (1.0f / NN));
    }
}

extern "C" void kernel_launch(void* const* d_in, const int* in_sizes, int n_in,
                              void* d_out, int out_size, void* d_ws, size_t ws_size,
                              hipStream_t stream) {
    const float* x   = (const float*)d_in[0];
    const float* W1  = (const float*)d_in[1];
    const float* b1  = (const float*)d_in[2];
    const float* W2  = (const float*)d_in[3];
    const float* b2  = (const float*)d_in[4];
    const float* mp1 = (const float*)d_in[5];
    const float* mn1 = (const float*)d_in[6];
    const float* mp2 = (const float*)d_in[7];
    const float* mn2 = (const float*)d_in[8];
    const int* e1 = (const int*)d_in[9];
    const int* e2 = (const int*)d_in[10];
    const int* perm1 = (const int*)d_in[11];
    const int* perm2 = (const int*)d_in[12];
    const int* src1 = e1;       const int* dst1 = e1 + NE;
    const int* src2 = e2;       const int* dst2 = e2 + NE;
    float* out = (float*)d_out;

    // workspace carve
    char* w = (char*)d_ws;
    _Float16* xwi1 = (_Float16*)w; w += (size_t)NN * 256 * 2;  // 25.6 MB interleaved
    _Float16* xwi2 = (_Float16*)w; w += (size_t)NN * 256 * 2;
    int* rp1 = (int*)w;   w += (size_t)(NN + 4) * 4;
    int* rp2 = (int*)w;   w += (size_t)(NN + 4) * 4;
    int* col1 = (int*)w;  w += (size_t)NE * 4;
    int* col2 = (int*)w;  w += (size_t)NE * 4;
    float* dinv1 = (float*)w; w += (size_t)NN * 4;
    float* dinv2 = (float*)w; w += (size_t)NN * 4;
    int* bcnt  = (int*)w; w += (size_t)1024 * 4;
    int2* bsd1 = (int2*)w; w += (size_t)NBKT * 8 * SCAP * 8;   // 8 MB each
    int2* bsd2 = (int2*)w; w += (size_t)NBKT * 8 * SCAP * 8;
    _Float16* wt1 = (_Float16*)w; w += (size_t)D * D * 2;  // 32 KB transposed half W
    _Float16* wt2 = (_Float16*)w; w += (size_t)D * D * 2;
    int* pinv1 = (int*)w; w += (size_t)NN * 4;
    int* pinv2 = (int*)w; w += (size_t)NN * 4;

    float* s1 = out + 12800000L;
    float* s2 = out + 25600128L;
    const float* pos1 = out;
    const float* pos2 = out + 12800128L;

    k_init<<<dim3(196), 256, 0, stream>>>(s1, s2, bcnt, W1, W2, wt1, wt2,
                                          perm1, perm2, pinv1, pinv2);
    k_bucket_gemm<<<dim3(BKT_BLOCKS + GEMM_BLOCKS), 256, 0, stream>>>(
        src1, dst1, src2, dst2, bcnt, bsd1, bsd2,
        wt1, wt2, x, mp1, mn1, mp2, mn2, pinv1, pinv2, xwi1, xwi2);
    k_build<<<dim3(128), 512, 0, stream>>>(bcnt, bsd1, bsd2,
                                           rp1, rp2, col1, col2, dinv1, dinv2);
    k_agg<<<dim3(12500, 2), 256, 0, stream>>>(xwi1, xwi2,
                                              rp1, col1, dinv1, rp2, col2, dinv2,
                                              b1, b2, out);
    k_sum<<<dim3(512, 2), 256, 0, stream>>>(pos1, pos2, s1, s2);
}